// Round 6
// baseline (98.284 us; speedup 1.0000x reference)
//
#include <hip/hip_runtime.h>

// Problem constants
#define N_FILTERS 1024
#define B_TOTAL   1024
#define IMG       64            // H = W = 64
#define PAD_DIM   70            // 64 + 2*3 padded image side
// Xt layout in d_ws: fp16 [8 bg][PAD_DIM*PAD_DIM pixels][128 batches]  (10 MB).
// bg-major: each XCD's hot slice (4900 px * 256 B = 1.25 MB) is CONTIGUOUS and
// pixel stride is 256 B, so the 10 column loads per window row fold into
// 13-bit immediate offsets (wc*256 <= 2304).
// Window consumed per filter: padded rows i..i+9, cols j..j+9 (pool floor mode
// discards conv row/col 6, so only a 10x10 slab of the 11x11 window is read).
//
// LESSONS:
//  r1-r2: __launch_bounds__ min-waves on gfx950 caps VGPRs ~2x harder than
//         512/N -> (256,4)=64 VGPR, (256,6)=40 VGPR, 60-145 MB scratch spills.
//         Fix: no min-waves arg, let the allocator pick.
//  r3:    one-batch-per-lane removed spills but lost v_pk_fma_f32 packing.
//  r5:    packed + lazy-init + early-fold, dur 97.5 (best). Inferred
//         filters_main ~27-30 us vs ~9 us floor -> latency-stall theory.
//  r6:    column-sliding cvt (-18 VGPR) + triple-buffered rows (2-row / ~1000
//         cycle prefetch distance). Same accumulation order (bit-identical).
//  fixed: harness re-poisons the 256 MiB workspace every iter (~45 us fill
//         inside the timed window) + ~15 us launch/graph overhead.
//         Controllable budget = dur - ~63.

typedef _Float16 half2_t __attribute__((ext_vector_type(2)));
typedef float    fvec2  __attribute__((ext_vector_type(2)));

// ---------------- prep: transpose + border-zero fused in one launch ----------------
// Blocks 0..1023: transpose X [1024 b][4096 p] -> Xt fp16 bg-major.
// Blocks 1024..1827: zero one border pixel each (804 px * 8 bg * 256 B).
__global__ __launch_bounds__(256) void prep_kernel(
    const float* __restrict__ X, _Float16* __restrict__ Xt)
{
    const int bid = blockIdx.x;
    if (bid >= 1024) {
        int pb = bid - 1024;              // 0..803
        int r, c;
        if (pb < 420) {
            int r6 = pb / 70;             // 0..5
            c = pb - r6 * 70;
            r = (r6 < 3) ? r6 : r6 + 64;  // rows 0,1,2,67,68,69
        } else {
            int q = pb - 420;
            r = 3 + q / 6;
            int k = q - (q / 6) * 6;      // 0..5
            c = (k < 3) ? k : k + 64;     // cols 0,1,2,67,68,69
        }
        const size_t pp = (size_t)r * PAD_DIM + c;
        const int bg = threadIdx.x >> 5, l = threadIdx.x & 31;
        unsigned long long* qp = (unsigned long long*)Xt
            + (size_t)bg * (4900ull * 32) + pp * 32 + l;
        *qp = 0ull;
        return;
    }

    __shared__ float T[64 * 65];         // [b_local][p_local], stride 65 kills conflicts
    const int pt = bid & 63;             // pixel tile (64 pixels)
    const int bt = bid >> 6;             // batch tile (64 batches)
    const int tx = threadIdx.x & 63, ty = threadIdx.x >> 6;

    #pragma unroll
    for (int pass = 0; pass < 16; ++pass) {
        int bl = pass * 4 + ty;          // lanes: consecutive pixels -> coalesced read
        T[bl * 65 + tx] = X[(size_t)(bt * 64 + bl) * 4096 + pt * 64 + tx];
    }
    __syncthreads();

    // write half2 (two consecutive batches) per lane -> dword stores, 8 passes
    const int h = threadIdx.x & 31;      // half2 index: batches 2h, 2h+1 of this 64-tile
    const int v = threadIdx.x >> 5;      // pixel sub-row 0..7
    half2_t* Xt2 = (half2_t*)Xt;
    #pragma unroll
    for (int pass = 0; pass < 8; ++pass) {
        int pl = pass * 8 + v;
        int p  = pt * 64 + pl;
        int r  = p >> 6, c = p & 63;
        half2_t val;
        val.x = (_Float16)T[(2 * h) * 65 + pl];
        val.y = (_Float16)T[(2 * h + 1) * 65 + pl];
        // batch b = bt*64 + 2h -> slice bg = bt>>1, half2 idx (bt&1)*32 + h
        Xt2[((size_t)(bt >> 1) * 4900 + (size_t)(r + 3) * PAD_DIM + (c + 3)) * 64
            + (bt & 1) * 32 + h] = val;
    }
}

// ---------------- main: 2 batches/lane, column-sliding cvt, 3-buffer prefetch ----------------
// Block = 4 waves = 4 filters, 128 batches (2/lane). Grid 2048: bg = bid&7 pins
// the XCD slice. acc[y][x] first touched at (wr==y, wc==x) (lazy init); conv
// row fy folds into pmax at wr==fy+4 and dies -> peak live acc rows = 5.
// Triple-buffered rows: loads issued 2 compute-rows (~1000 cy) before use.

#define LOAD_ROW(buf, WR) do {                                                  \
    const half2_t* rp_ = Xg + (size_t)((si + (WR)) * PAD_DIM + sj) * 64;        \
    _Pragma("unroll")                                                           \
    for (int wc = 0; wc < 10; ++wc) buf[wc] = rp_[wc * 64];                     \
} while (0)

#define COMPUTE_ROW(buf, WR) do {                                               \
    const int ylo = (((WR) > 4) ? ((WR) - 4) : 0);                              \
    const int yhi = (((WR) < 5) ? (WR) : 5);                                    \
    _Pragma("unroll")                                                           \
    for (int wc = 0; wc < 10; ++wc) {                                           \
        fvec2 v_;                                                               \
        v_.x = (float)buf[wc].x;                                                \
        v_.y = (float)buf[wc].y;                                                \
        const int xlo = ((wc > 4) ? (wc - 4) : 0);                              \
        const int xhi = ((wc < 5) ? wc : 5);                                    \
        _Pragma("unroll")                                                       \
        for (int y = 0; y < 6; ++y) {                                           \
            if (y >= ylo && y <= yhi) {                                         \
                _Pragma("unroll")                                               \
                for (int x = 0; x < 6; ++x) {                                   \
                    if (x >= xlo && x <= xhi) {                                 \
                        const fvec2 wv = (fvec2)wk[((WR) - y) * 5 + (wc - x)];  \
                        if (y == (WR) && x == wc)      /* first touch */        \
                            acc[y * 6 + x] = wv * v_;                           \
                        else                                                    \
                            acc[y * 6 + x] = wv * v_ + acc[y * 6 + x];          \
                    }                                                           \
                }                                                               \
            }                                                                   \
        }                                                                       \
    }                                                                           \
    if ((WR) >= 4) {                        /* conv row fy is complete: fold */ \
        const int fy = (WR) - 4;                                                \
        _Pragma("unroll")                                                       \
        for (int px = 0; px < 2; ++px) {                                        \
            fvec2 a0 = acc[fy * 6 + 3 * px];                                    \
            fvec2 a1 = acc[fy * 6 + 3 * px + 1];                                \
            fvec2 a2 = acc[fy * 6 + 3 * px + 2];                                \
            fvec2 m_;                                                           \
            m_.x = fmaxf(fmaxf(a0.x, a1.x), a2.x);                              \
            m_.y = fmaxf(fmaxf(a0.y, a1.y), a2.y);                              \
            const int pi = ((fy >= 3) ? 2 : 0) + px;                            \
            if (fy == 0 || fy == 3) {       /* fresh pool cell, no init */      \
                pmax[pi] = m_;                                                  \
            } else {                                                            \
                pmax[pi].x = fmaxf(pmax[pi].x, m_.x);                           \
                pmax[pi].y = fmaxf(pmax[pi].y, m_.y);                           \
            }                                                                   \
        }                                                                       \
    }                                                                           \
} while (0)

__global__ __launch_bounds__(256) void filters_main(
    const half2_t* __restrict__ Xt2,   // [8 bg][4900 px][64 half2]
    const float*   __restrict__ W,     // [F][25]
    const float*   __restrict__ bias,  // [F]
    const int*     __restrict__ pos,   // [F][2]
    float4*        __restrict__ out4)  // [B][1024 float4]  (= [B][F*4] floats)
{
    const int t    = threadIdx.x;
    const int lane = t & 63;
    const int w    = t >> 6;                       // wave id 0..3
    const int bg   = blockIdx.x & 7;               // batch group (128 b) = XCD pin
    const int fg   = blockIdx.x >> 3;              // filter group (4 filters)

    const int f  = fg * 4 + w;
    const int sf = __builtin_amdgcn_readfirstlane(f);
    const int si = __builtin_amdgcn_readfirstlane(pos[2 * sf]);       // row i, 0..59
    const int sj = __builtin_amdgcn_readfirstlane(pos[2 * sf + 1]);   // col j, 0..59

    float wk[25];
    const float* wp = W + sf * 25;                 // scalar address -> s_load into SGPRs
    #pragma unroll
    for (int k = 0; k < 25; ++k) wk[k] = wp[k];

    // lane handles batches (2*lane, 2*lane+1) of slice bg: half2 index = lane
    const half2_t* Xg = Xt2 + (size_t)bg * (4900ull * 64) + lane;

    fvec2 acc[36];    // lazily initialized; peak live = 5 rows (30 fvec2)
    fvec2 pmax[4];    // lazily initialized at fy==0 / fy==3

    half2_t bufA[10], bufB[10], bufC[10];
    LOAD_ROW(bufA, 0);
    LOAD_ROW(bufB, 1);
    LOAD_ROW(bufC, 2);
    COMPUTE_ROW(bufA, 0);  LOAD_ROW(bufA, 3);
    COMPUTE_ROW(bufB, 1);  LOAD_ROW(bufB, 4);
    COMPUTE_ROW(bufC, 2);  LOAD_ROW(bufC, 5);
    COMPUTE_ROW(bufA, 3);  LOAD_ROW(bufA, 6);
    COMPUTE_ROW(bufB, 4);  LOAD_ROW(bufB, 7);
    COMPUTE_ROW(bufC, 5);  LOAD_ROW(bufC, 8);
    COMPUTE_ROW(bufA, 6);  LOAD_ROW(bufA, 9);
    COMPUTE_ROW(bufB, 7);
    COMPUTE_ROW(bufC, 8);
    COMPUTE_ROW(bufA, 9);

    // ---- epilogue: merge 4 waves' outputs into full 64 B stores via LDS ----
    const float bv = bias[sf];
    __shared__ float S[4][128][5];                 // batch stride 5 -> conflict-light
    #pragma unroll
    for (int k = 0; k < 4; ++k) {
        S[w][2 * lane][k]     = pmax[k].x + bv;
        S[w][2 * lane + 1][k] = pmax[k].y + bv;
    }
    __syncthreads();

    // thread t -> filter-sub q = t&3, batch r0 = t>>2 (+64 on 2nd pass);
    // 4 consecutive lanes write one contiguous 64 B line out[b][fg*16..+15].
    const int q = t & 3, r0 = t >> 2;
    #pragma unroll
    for (int half = 0; half < 2; ++half) {
        const int b = r0 + half * 64;
        float4 val;
        val.x = S[q][b][0];
        val.y = S[q][b][1];
        val.z = S[q][b][2];
        val.w = S[q][b][3];
        out4[(size_t)(bg * 128 + b) * 1024 + fg * 4 + q] = val;
    }
}

extern "C" void kernel_launch(void* const* d_in, const int* in_sizes, int n_in,
                              void* d_out, int out_size, void* d_ws, size_t ws_size,
                              hipStream_t stream) {
    const float* X    = (const float*)d_in[0];
    const float* W    = (const float*)d_in[1];
    const float* bias = (const float*)d_in[2];
    const int*   pos  = (const int*)d_in[3];
    float4* out4 = (float4*)d_out;
    _Float16* Xt = (_Float16*)d_ws;        // 8*4900*128 fp16 = 10 MB

    prep_kernel<<<1024 + 804, 256, 0, stream>>>(X, Xt);
    filters_main<<<2048, 256, 0, stream>>>((const half2_t*)Xt, W, bias, pos, out4);
}